// Round 2
// baseline (109.710 us; speedup 1.0000x reference)
//
#include <hip/hip_runtime.h>

// Haar IDWT, fully collapsed:
//   out[b, oi, oj] = 0.5 * ( (ll+lh) + sgn_j*hl + sgn_i*sgn_j*hh )
//   coeffs at (b, oi>>1, oj>>1, 0..3); sgn_i=+1 iff oi odd; sgn_j=+1 iff oj odd.
// Symmetric padding in the reference is never sampled after the crop (index
// algebra collapses to orig row/col = o>>1), so no boundary handling.
//
// Layout: each thread owns a VERTICAL pair of coefficient sites
// (y0, x) and (y0+1, x).  Within a wave, x is consecutive across lanes, so:
//   - loads:  2 x global_load_dwordx4, 16 B/lane, lane-contiguous (1 KB/wave)
//   - stores: 4 rows x global_store_dwordx2, 8 B/lane, lane-contiguous
// Every memory instruction is perfectly coalesced (no strided interleave,
// unlike the horizontal-pair variant which touched each line twice).

__global__ __launch_bounds__(256) void idwt_haar_kernel(
        const float* __restrict__ in, float* __restrict__ out) {
    int tid = blockIdx.x * 256 + threadIdx.x;
    int x  = tid & 511;          // coefficient column 0..511
    int yq = (tid >> 9) & 255;   // vertical site-pair index: rows 2*yq, 2*yq+1
    int b  = tid >> 17;          // batch

    int y0 = 2 * yq;
    const float4* in4 = reinterpret_cast<const float4*>(in)
                      + ((size_t)(b * 512 + y0) * 512 + x);
    float4 c0 = in4[0];      // site (y0,   x)
    float4 c1 = in4[512];    // site (y0+1, x)

    // c.x=ll, c.y=lh, c.z=hl, c.w=hh  (reference fuses ll+lh by linearity)
    float a0 = c0.x + c0.y, h0 = c0.z, d0 = c0.w;
    float a1 = c1.x + c1.y, h1 = c1.z, d1 = c1.w;

    // even output row: {a-h+d, a+h-d}; odd output row: {a-h-d, a+h+d}
    float2 r0 = make_float2(0.5f * (a0 - h0 + d0), 0.5f * (a0 + h0 - d0));
    float2 r1 = make_float2(0.5f * (a0 - h0 - d0), 0.5f * (a0 + h0 + d0));
    float2 r2 = make_float2(0.5f * (a1 - h1 + d1), 0.5f * (a1 + h1 - d1));
    float2 r3 = make_float2(0.5f * (a1 - h1 - d1), 0.5f * (a1 + h1 + d1));

    size_t obase = ((size_t)b * 1024 + 2 * y0) * 1024 + 2 * x;
    float2* o = reinterpret_cast<float2*>(out + obase);
    o[0]          = r0;   // row 2*y0
    o[512]        = r1;   // row 2*y0+1   (1024 floats = 512 float2)
    o[1024]       = r2;   // row 2*y0+2
    o[1536]       = r3;   // row 2*y0+3
}

extern "C" void kernel_launch(void* const* d_in, const int* in_sizes, int n_in,
                              void* d_out, int out_size, void* d_ws, size_t ws_size,
                              hipStream_t stream) {
    const float* in = (const float*)d_in[0];
    float* out = (float*)d_out;
    // total threads: 16 batches * 256 row-pairs * 512 cols = 2,097,152
    int total = 16 * 256 * 512;
    idwt_haar_kernel<<<total / 256, 256, 0, stream>>>(in, out);
}